// Round 9
// baseline (437.166 us; speedup 1.0000x reference)
//
#include <hip/hip_runtime.h>
#include <stdint.h>

typedef unsigned short u16;
typedef __attribute__((ext_vector_type(4))) float f32x4;
typedef __attribute__((ext_vector_type(16))) float f32x16;
typedef __attribute__((ext_vector_type(8))) short s16x8;
typedef __attribute__((ext_vector_type(8))) __bf16 bf16x8;
typedef __attribute__((ext_vector_type(8))) unsigned short u16x8;
typedef __attribute__((ext_vector_type(4))) unsigned short u16x4;
typedef __attribute__((ext_vector_type(4))) uint32_t u32x4;
typedef __attribute__((ext_vector_type(2))) uint32_t u32x2;

__device__ __forceinline__ f32x4 mfma16(s16x8 a, s16x8 b, f32x4 c) {
  return __builtin_amdgcn_mfma_f32_16x16x32_bf16(
      __builtin_bit_cast(bf16x8, a), __builtin_bit_cast(bf16x8, b), c, 0, 0, 0);
}
__device__ __forceinline__ f32x16 mfma32(s16x8 a, s16x8 b, f32x16 c) {
  return __builtin_amdgcn_mfma_f32_32x32x16_bf16(
      __builtin_bit_cast(bf16x8, a), __builtin_bit_cast(bf16x8, b), c, 0, 0, 0);
}

__device__ __forceinline__ void gl_lds16(const u16* g, u16* l) {
  __builtin_amdgcn_global_load_lds(
      (const __attribute__((address_space(1))) void*)g,
      (__attribute__((address_space(3))) void*)l, 16, 0, 0);
}

__device__ __forceinline__ u16 bf16rne(float f) {
  uint32_t u = __builtin_bit_cast(uint32_t, f);
  u += 0x7fffu + ((u >> 16) & 1u);
  return (u16)(u >> 16);
}

// ------- cast W -> Wt[768][2048] bf16 (WQ rows pre-scaled by scale*log2e) -------
__global__ void cast_w_kernel(const float* __restrict__ WQ, const float* __restrict__ WK,
                              const float* __restrict__ WV, u16* __restrict__ Wt, float qscale) {
  int i = blockIdx.x * 256 + threadIdx.x;  // 768*2048 threads
  int r = i >> 11, k = i & 2047;
  int sel = r >> 8, c = r & 255;
  const float* W = (sel == 0) ? WQ : (sel == 1) ? WK : WV;
  float v = W[(size_t)k * 256 + c];
  if (sel == 0) v *= qscale;
  Wt[i] = bf16rne(v);
}

// ---------------- QKV projection GEMM: [16384,2048] x [2048,768] ----------------
// Fused x-cast + T3/T4 counted-vmcnt raw-barrier pipeline. A (f32 x) is
// reg-staged two tiles deep (aregE/aregO); the per-iter barrier waits
// vmcnt(4) — draining only the 2 older stageB gl_lds16 ops while the 4 newer
// A-loads stay in flight ACROSS the barrier (a standard __syncthreads would
// force vmcnt(0) and cap the pipeline at one compute phase — R8's 134us,
// MfmaUtil 15%). writeA is placed first-after-barrier so the compiler's
// register-dependency wait lands one full iteration after load issue.
__global__ __launch_bounds__(256) void proj_gemm(const float* __restrict__ x, const u16* __restrict__ Wt,
                                                 u16* __restrict__ Qb, u16* __restrict__ Kb,
                                                 u16* __restrict__ Vt) {
  const int bid = blockIdx.x;             // 768 blocks
  const int xcd = bid & 7, j = bid >> 3;  // j in 0..95
  const int m0 = (xcd * 16 + (j / 6)) * 128;
  const int n0 = (j % 6) * 128;
  const int tid = threadIdx.x, lane = tid & 63, w = tid >> 6;
  const int ln = lane & 15, quad = lane >> 4;
  const int wm = w & 1, wn = w >> 1;
  __shared__ __align__(16) u16 As[2][128 * 32];
  __shared__ __align__(16) u16 Bs[2][128 * 32];
  f32x4 acc[4][4];
#pragma unroll
  for (int i = 0; i < 4; ++i)
#pragma unroll
    for (int jj = 0; jj < 4; ++jj) acc[i][jj] = f32x4{0.f, 0.f, 0.f, 0.f};

  auto stageB = [&](int kk, int bi) {
#pragma unroll
    for (int i = 0; i < 2; ++i) {
      int p = tid + i * 256;
      int row = p >> 2, cg = (p & 3) ^ (row & 3);
      gl_lds16(Wt + (size_t)(n0 + row) * 2048 + kk + cg * 8, Bs[bi] + (size_t)(p - lane) * 8);
    }
  };

  // Two A-register sets: E holds even tiles, O holds odd tiles (static names
  // via 2-way loop unroll — rule #20: no runtime-indexed reg arrays).
  f32x4 aregE[2][2], aregO[2][2];
  auto loadA = [&](f32x4 (&ar)[2][2], int kk) {
#pragma unroll
    for (int i = 0; i < 2; ++i) {
      int p = tid + i * 256;
      int row = p >> 2, cg = (p & 3) ^ (row & 3);
      const float* src = x + (size_t)(m0 + row) * 2048 + kk + cg * 8;
      ar[i][0] = *(const f32x4*)src;
      ar[i][1] = *(const f32x4*)(src + 4);
    }
  };
  auto writeA = [&](int bi, f32x4 (&ar)[2][2]) {
#pragma unroll
    for (int i = 0; i < 2; ++i) {
      int p = tid + i * 256;
      u16x8 o;
#pragma unroll
      for (int jj = 0; jj < 4; ++jj) {
        o[jj] = __builtin_bit_cast(u16, (__bf16)ar[i][0][jj]);
        o[4 + jj] = __builtin_bit_cast(u16, (__bf16)ar[i][1][jj]);
      }
      *(u16x8*)(As[bi] + (size_t)p * 8) = o;
    }
  };
  auto computeTile = [&](int bi) {
    const u16* Asb = As[bi];
    const u16* Bsb = Bs[bi];
    s16x8 a[4];
#pragma unroll
    for (int mt = 0; mt < 4; ++mt) {
      int r = wm * 64 + mt * 16 + ln;
      a[mt] = *(const s16x8*)(Asb + r * 32 + ((quad ^ (r & 3)) * 8));
    }
#pragma unroll
    for (int nt = 0; nt < 4; ++nt) {
      int r = wn * 64 + nt * 16 + ln;
      s16x8 bf = *(const s16x8*)(Bsb + r * 32 + ((quad ^ (r & 3)) * 8));
#pragma unroll
      for (int mt = 0; mt < 4; ++mt) acc[mt][nt] = mfma16(a[mt], bf, acc[mt][nt]);
    }
  };

  // prologue: tiles 0,1 into regs; B tile0; A tile0 -> LDS.
  loadA(aregE, 0);
  loadA(aregO, 32);
  stageB(0, 0);
  writeA(0, aregE);  // compiler drains the tile-0 loads here (startup only)

  // Main loop: t = 0,2,...,60 (31 double-iters, tiles 0..61 computed).
  // Invariant at each barrier: in flight = stageB(2, older) + loadA(4, newer);
  // vmcnt(4) retires exactly the stageB pair; lgkmcnt(0) publishes ds_writes
  // and completes compute's ds_reads before buffers are overwritten.
  for (int t = 0; t < 62; t += 2) {
    // ---- even half: compute tile t from As[0]/Bs[0]
    asm volatile("s_waitcnt vmcnt(4) lgkmcnt(0)" ::: "memory");
    __builtin_amdgcn_s_barrier();
    __builtin_amdgcn_sched_barrier(0);
    writeA(1, aregO);              // tile t+1 (loads issued one iter ago)
    stageB((t + 1) * 32, 1);
    loadA(aregE, (t + 2) * 32);    // tile t+2, stays in flight across barrier
    computeTile(0);
    // ---- odd half: compute tile t+1 from As[1]/Bs[1]
    asm volatile("s_waitcnt vmcnt(4) lgkmcnt(0)" ::: "memory");
    __builtin_amdgcn_s_barrier();
    __builtin_amdgcn_sched_barrier(0);
    writeA(0, aregE);              // tile t+2
    stageB((t + 2) * 32, 0);
    loadA(aregO, (t + 3) * 32);    // tile t+3 (t+3 <= 63 for all main-loop t)
    computeTile(1);
  }
  // ---- peel t=62: in flight = stageB(62->Bs[0]) + loadA(tile63)
  asm volatile("s_waitcnt vmcnt(4) lgkmcnt(0)" ::: "memory");
  __builtin_amdgcn_s_barrier();
  __builtin_amdgcn_sched_barrier(0);
  writeA(1, aregO);                // tile 63
  stageB(63 * 32, 1);
  computeTile(0);                  // tile 62
  // ---- peel t=63: drain everything (no loads in flight to preserve)
  asm volatile("s_waitcnt vmcnt(0) lgkmcnt(0)" ::: "memory");
  __builtin_amdgcn_s_barrier();
  __builtin_amdgcn_sched_barrier(0);
  computeTile(1);                  // tile 63

#pragma unroll
  for (int mt = 0; mt < 4; ++mt)
#pragma unroll
    for (int nt = 0; nt < 4; ++nt) {
      int row0 = m0 + wm * 64 + mt * 16 + quad * 4;
      int col = n0 + wn * 64 + nt * 16 + ln;
      int sel = col >> 8, c = col & 255;
      u16x4 vv;
#pragma unroll
      for (int jj = 0; jj < 4; ++jj) vv[jj] = bf16rne(acc[mt][nt][jj]);
      if (sel == 2) {
        int b = row0 >> 12, s = row0 & 4095;
        *(u16x4*)(Vt + (size_t)b * 1048576 + (size_t)c * 4096 + s) = vv;
      } else {
        u16* dst = (sel == 0) ? Qb : Kb;
#pragma unroll
        for (int jj = 0; jj < 4; ++jj) dst[(size_t)(row0 + jj) * 256 + c] = vv[jj];
      }
    }
}

// ---------------- lambda scalar ----------------
__global__ void lam_kernel(const float* __restrict__ lq1, const float* __restrict__ lq2,
                           const float* __restrict__ lk1, const float* __restrict__ lk2,
                           float* __restrict__ lamp) {
  int t = threadIdx.x;  // 64 threads
  float d1 = lq1[t] * lk1[t] + lq1[t + 64] * lk1[t + 64];
  float d2 = lq2[t] * lk2[t] + lq2[t + 64] * lk2[t + 64];
#pragma unroll
  for (int off = 32; off; off >>= 1) {
    d1 += __shfl_xor(d1, off);
    d2 += __shfl_xor(d2, off);
  }
  if (t == 0) *lamp = expf(d1) + expf(d2) + (0.8f - 0.6f * expf(-3.6f));
}

// ------- fused flash attention: 64 q-rows/block, 8 waves, dbuf staging -------
// R5/R6/R8-proven: ~123 us, MfmaUtil 38, no spills. Unchanged this round.
__global__ __launch_bounds__(512, 2) void attn_kernel(const u16* __restrict__ Qb,
                                                      const u16* __restrict__ Kb,
                                                      const u16* __restrict__ Vt,
                                                      const float* __restrict__ lamp,
                                                      float* __restrict__ out) {
  const int bid = blockIdx.x;
  const int xcd = bid & 7;
  const int b = xcd >> 1;
  const int qt = ((bid >> 3) << 1) + (xcd & 1);  // 0..63, q rows qt*64..+64
  const int tid = threadIdx.x, lane = tid & 63, w = tid >> 6;
  const int l5 = lane & 31, lh = lane >> 5;
  const int m = w & 1, kt = (w >> 1) & 1, qh = w >> 2;

  // dbuf: two 64KB buffers [Ks 32KB | Vs 32KB]; epilogue overlays the lot.
  __shared__ __align__(16) char smem[134144];
  float* buf0 = (float*)smem;            // epilogue: map0 O^T [256][65]
  float* buf1 = (float*)(smem + 66560);  // epilogue: map1 O^T [256][65]
  float* ls = (float*)(smem + 133120);   // l partials [w][32]

  const u16* Kg0 = Kb + ((size_t)b * 4096) * 256;
  const u16* Vg0 = Vt + (size_t)b * 1048576;

  auto stage = [&](int kb, char* base) {
    u16* Ks = (u16*)base;
    u16* Vs = (u16*)(base + 32768);
#pragma unroll
    for (int i = 0; i < 4; ++i) {
      int p = tid + i * 512;
      int row = p >> 5, c = p & 31;
      int cg = (c & 16) | ((c ^ row) & 15);
      gl_lds16(Kg0 + (size_t)(kb + row) * 256 + cg * 8, Ks + (size_t)(p - lane) * 8);
    }
#pragma unroll
    for (int i = 0; i < 4; ++i) {
      int p = tid + i * 512;
      int row = p >> 3, c = p & 7;
      int cg = c ^ (row & 7);
      gl_lds16(Vg0 + (size_t)row * 4096 + kb + cg * 8, Vs + (size_t)(p - lane) * 8);
    }
  };

  // kick off tile 0 staging before anything else
  stage(0, smem);

  // Q^T B-frags: B[k=d][n=q]: lane q = l5 within slice qh, d = s*16 + lh*8 + j
  s16x8 bq[8];
  {
    const u16* qp =
        Qb + ((size_t)(b * 4096 + qt * 64 + qh * 32 + l5)) * 256 + m * 128 + lh * 8;
#pragma unroll
    for (int s = 0; s < 8; ++s) bq[s] = *(const s16x8*)(qp + s * 16);
  }

  f32x16 O[8];
#pragma unroll
  for (int ct = 0; ct < 8; ++ct)
#pragma unroll
    for (int r = 0; r < 16; ++r) O[ct][r] = 0.f;
  float l_run = 0.f;

  for (int t = 0; t < 64; ++t) {
    __syncthreads();  // stage(t) complete (vmcnt drain); compute(t-1) reads done
    if (t + 1 < 64) stage((t + 1) * 64, smem + ((t + 1) & 1) * 65536);

    char* base = smem + (t & 1) * 65536;
    u16* Ks = (u16*)base;
    u16* Vs = (u16*)(base + 32768);

    // S^T[32 keys][32 q] = K . Q^T for (map m, keys kt*32..+32); two chains
    f32x16 Sa, Sb;
#pragma unroll
    for (int r = 0; r < 16; ++r) { Sa[r] = 0.f; Sb[r] = 0.f; }
#pragma unroll
    for (int s = 0; s < 8; s += 2) {
      int row = kt * 32 + l5;
      int c0 = m * 16 + s * 2 + lh;
      int c1 = m * 16 + (s + 1) * 2 + lh;
      s16x8 a0 = *(const s16x8*)(Ks + row * 256 + (((c0 & 16) | ((c0 ^ row) & 15))) * 8);
      s16x8 a1 = *(const s16x8*)(Ks + row * 256 + (((c1 & 16) | ((c1 ^ row) & 15))) * 8);
      Sa = mfma32(a0, bq[s], Sa);
      Sb = mfma32(a1, bq[s + 1], Sb);
    }

    // pre-read all V frags into regs (PV becomes pure-reg; hides LDS latency)
    s16x8 vfr0[8], vfr1[8];
#pragma unroll
    for (int ct = 0; ct < 8; ++ct) {
      int row = ct * 32 + l5;
      int c0v = (kt * 32) / 8 + lh;
      int c1v = (kt * 32 + 16) / 8 + lh;
      vfr0[ct] = *(const s16x8*)(Vs + row * 64 + ((c0v ^ (row & 7)) * 8));
      vfr1[ct] = *(const s16x8*)(Vs + row * 64 + ((c1v ^ (row & 7)) * 8));
    }

    // p = exp2(s) via raw v_exp_f32; accumulate l; pack to dwords (bf16rne)
    uint32_t P[8];
#pragma unroll
    for (int d = 0; d < 8; ++d) {
      float p0 = __builtin_amdgcn_exp2f(Sa[2 * d] + Sb[2 * d]);
      float p1 = __builtin_amdgcn_exp2f(Sa[2 * d + 1] + Sb[2 * d + 1]);
      l_run += p0 + p1;
      P[d] = (uint32_t)bf16rne(p0) | ((uint32_t)bf16rne(p1) << 16);
    }

    // PV: O^T[256 vcol][32 q] += V^T . P^T ; half-exchange via permlane32_swap:
    // swap(P[4k],P[4k+2]) -> (fd0,fd2), swap(P[4k+1],P[4k+3]) -> (fd1,fd3)
#pragma unroll
    for (int ks = 0; ks < 2; ++ks) {
      u32x2 s02 = __builtin_amdgcn_permlane32_swap(P[ks * 4 + 0], P[ks * 4 + 2], false, false);
      u32x2 s13 = __builtin_amdgcn_permlane32_swap(P[ks * 4 + 1], P[ks * 4 + 3], false, false);
      u32x4 fd;
      fd[0] = s02[0]; fd[1] = s13[0]; fd[2] = s02[1]; fd[3] = s13[1];
      s16x8 pf = __builtin_bit_cast(s16x8, fd);
      if (ks == 0) {
#pragma unroll
        for (int ct = 0; ct < 8; ++ct) O[ct] = mfma32(vfr0[ct], pf, O[ct]);
      } else {
#pragma unroll
        for (int ct = 0; ct < 8; ++ct) O[ct] = mfma32(vfr1[ct], pf, O[ct]);
      }
    }
  }

  // ---------------- epilogue ----------------
  float lam = *lamp;
  l_run += __shfl_xor(l_run, 32);  // fold lh (partner holds other 16 keys)
  __syncthreads();                 // B1: loop reads done; smem becomes buf0/buf1/ls
  if (lane < 32) ls[w * 32 + l5] = l_run;
  float* bufm = m ? buf1 : buf0;
  const int qb0 = qh * 32;
  if (kt == 1) {
#pragma unroll
    for (int ct = 0; ct < 8; ++ct)
#pragma unroll
      for (int r = 0; r < 16; ++r) {
        int vcol = ct * 32 + (r & 3) + 8 * (r >> 2) + 4 * lh;
        bufm[vcol * 65 + qb0 + l5] = O[ct][r];
      }
  }
  __syncthreads();  // B2
  if (kt == 0) {
    float linv = 1.f / (ls[w * 32 + l5] + ls[(w | 2) * 32 + l5]);
#pragma unroll
    for (int ct = 0; ct < 8; ++ct)
#pragma unroll
      for (int r = 0; r < 16; ++r) {
        int vcol = ct * 32 + (r & 3) + 8 * (r >> 2) + 4 * lh;
        bufm[vcol * 65 + qb0 + l5] = (O[ct][r] + bufm[vcol * 65 + qb0 + l5]) * linv;
      }
  }
  __syncthreads();  // B3
  // cooperative write: out[q][col], coalesced; 512 threads = 2 q-halves x 256 cols
  float* og = out + ((size_t)(b * 4096 + qt * 64)) * 256;
  const int col = tid & 255, half = tid >> 8;
#pragma unroll
  for (int j2 = 0; j2 < 32; ++j2) {
    int q = half * 32 + j2;
    float v = buf0[col * 65 + q] - lam * buf1[col * 65 + q];
    og[(size_t)q * 256 + col] = v;
  }
}

extern "C" void kernel_launch(void* const* d_in, const int* in_sizes, int n_in,
                              void* d_out, int out_size, void* d_ws, size_t ws_size,
                              hipStream_t stream) {
  (void)in_sizes; (void)n_in; (void)out_size; (void)ws_size;
  const float* x   = (const float*)d_in[0];
  const float* WQ  = (const float*)d_in[1];
  const float* WK  = (const float*)d_in[2];
  const float* WV  = (const float*)d_in[3];
  const float* lq1 = (const float*)d_in[4];
  const float* lq2 = (const float*)d_in[5];
  const float* lk1 = (const float*)d_in[6];
  const float* lk2 = (const float*)d_in[7];
  float* out = (float*)d_out;

  char* ws = (char*)d_ws;
  u16* Wt = (u16*)ws;   ws += (size_t)768 * 2048 * 2;
  u16* Qb = (u16*)ws;   ws += (size_t)16384 * 256 * 2;
  u16* Kb = (u16*)ws;   ws += (size_t)16384 * 256 * 2;
  u16* Vt = (u16*)ws;   ws += (size_t)16384 * 256 * 2;  // [b][col 256][s 4096]
  float* lamp = (float*)ws;

  const float qscale = 0.0883883476f * 1.44269504f;  // HEAD_DIM^-0.5 * log2(e)

  hipLaunchKernelGGL(cast_w_kernel, dim3(6144), dim3(256), 0, stream, WQ, WK, WV, Wt, qscale);
  hipLaunchKernelGGL(proj_gemm, dim3(768), dim3(256), 0, stream, x, Wt, Qb, Kb, Vt);
  hipLaunchKernelGGL(lam_kernel, dim3(1), dim3(64), 0, stream, lq1, lq2, lk1, lk2, lamp);
  hipLaunchKernelGGL(attn_kernel, dim3(256), dim3(512), 0, stream, Qb, Kb, Vt, lamp, out);
}

// Round 10
// 384.235 us; speedup vs baseline: 1.1378x; 1.1378x over previous
//
#include <hip/hip_runtime.h>
#include <stdint.h>

typedef unsigned short u16;
typedef __attribute__((ext_vector_type(4))) float f32x4;
typedef __attribute__((ext_vector_type(16))) float f32x16;
typedef __attribute__((ext_vector_type(8))) short s16x8;
typedef __attribute__((ext_vector_type(8))) __bf16 bf16x8;
typedef __attribute__((ext_vector_type(8))) unsigned short u16x8;
typedef __attribute__((ext_vector_type(4))) unsigned short u16x4;
typedef __attribute__((ext_vector_type(4))) uint32_t u32x4;
typedef __attribute__((ext_vector_type(2))) uint32_t u32x2;

__device__ __forceinline__ f32x4 mfma16(s16x8 a, s16x8 b, f32x4 c) {
  return __builtin_amdgcn_mfma_f32_16x16x32_bf16(
      __builtin_bit_cast(bf16x8, a), __builtin_bit_cast(bf16x8, b), c, 0, 0, 0);
}
__device__ __forceinline__ f32x16 mfma32(s16x8 a, s16x8 b, f32x16 c) {
  return __builtin_amdgcn_mfma_f32_32x32x16_bf16(
      __builtin_bit_cast(bf16x8, a), __builtin_bit_cast(bf16x8, b), c, 0, 0, 0);
}

__device__ __forceinline__ void gl_lds16(const u16* g, u16* l) {
  __builtin_amdgcn_global_load_lds(
      (const __attribute__((address_space(1))) void*)g,
      (__attribute__((address_space(3))) void*)l, 16, 0, 0);
}

__device__ __forceinline__ u16 bf16rne(float f) {
  uint32_t u = __builtin_bit_cast(uint32_t, f);
  u += 0x7fffu + ((u >> 16) & 1u);
  return (u16)(u >> 16);
}

// ------- merged prologue: cast x, cast W (+qscale), lambda — one launch -------
// blocks [0,16384): x -> xb bf16 (8 elems/thread)
// blocks [16384,22528): W -> Wt[768][2048] bf16, WQ rows pre-scaled
// block 22528: lambda scalar (wave 0 only)
__global__ void pre_kernel(const float* __restrict__ x, const float* __restrict__ WQ,
                           const float* __restrict__ WK, const float* __restrict__ WV,
                           const float* __restrict__ lq1, const float* __restrict__ lq2,
                           const float* __restrict__ lk1, const float* __restrict__ lk2,
                           u16* __restrict__ xb, u16* __restrict__ Wt,
                           float* __restrict__ lamp, float qscale) {
  const int blk = blockIdx.x, tid = threadIdx.x;
  if (blk < 16384) {
    size_t i = ((size_t)blk * 256 + tid) * 8;
    f32x4 a = *(const f32x4*)(x + i);
    f32x4 b = *(const f32x4*)(x + i + 4);
    u16x8 o;
#pragma unroll
    for (int j = 0; j < 4; ++j) { o[j] = bf16rne(a[j]); o[4 + j] = bf16rne(b[j]); }
    *(u16x8*)(xb + i) = o;
  } else if (blk < 22528) {
    int i = (blk - 16384) * 256 + tid;  // 768*2048 elements
    int r = i >> 11, k = i & 2047;
    int sel = r >> 8, c = r & 255;
    const float* W = (sel == 0) ? WQ : (sel == 1) ? WK : WV;
    float v = W[(size_t)k * 256 + c];
    if (sel == 0) v *= qscale;
    Wt[i] = bf16rne(v);
  } else {
    if (tid < 64) {
      int t = tid;
      float d1 = lq1[t] * lk1[t] + lq1[t + 64] * lk1[t + 64];
      float d2 = lq2[t] * lk2[t] + lq2[t + 64] * lk2[t + 64];
#pragma unroll
      for (int off = 32; off; off >>= 1) {
        d1 += __shfl_xor(d1, off);
        d2 += __shfl_xor(d2, off);
      }
      if (t == 0) *lamp = expf(d1) + expf(d2) + (0.8f - 0.6f * expf(-3.6f));
    }
  }
}

// ---------------- QKV projection GEMM: [16384,2048] x [2048,768] ----------------
// R6-proven form: both operands bf16 via global_load_lds, single-barrier dbuf
// (barrier at top of iter t drains stage(t), which overlapped compute(t-1)).
// XCD-swizzled; V written transposed: Vt[b][col][s]. LDS 2x(8KB+8KB)=32KB.
__global__ __launch_bounds__(256) void proj_gemm(const u16* __restrict__ xb, const u16* __restrict__ Wt,
                                                 u16* __restrict__ Qb, u16* __restrict__ Kb,
                                                 u16* __restrict__ Vt) {
  const int bid = blockIdx.x;             // 768 blocks
  const int xcd = bid & 7, j = bid >> 3;  // j in 0..95
  const int m0 = (xcd * 16 + (j / 6)) * 128;
  const int n0 = (j % 6) * 128;
  const int tid = threadIdx.x, lane = tid & 63, w = tid >> 6;
  const int ln = lane & 15, quad = lane >> 4;
  const int wm = w & 1, wn = w >> 1;
  __shared__ __align__(16) u16 As[2][128 * 32];
  __shared__ __align__(16) u16 Bs[2][128 * 32];
  f32x4 acc[4][4];
#pragma unroll
  for (int i = 0; i < 4; ++i)
#pragma unroll
    for (int jj = 0; jj < 4; ++jj) acc[i][jj] = f32x4{0.f, 0.f, 0.f, 0.f};

  auto stage = [&](int kk, int bi) {
#pragma unroll
    for (int i = 0; i < 2; ++i) {
      int p = tid + i * 256;
      int row = p >> 2, cg = (p & 3) ^ (row & 3);
      gl_lds16(xb + (size_t)(m0 + row) * 2048 + kk + cg * 8, As[bi] + (size_t)(p - lane) * 8);
      gl_lds16(Wt + (size_t)(n0 + row) * 2048 + kk + cg * 8, Bs[bi] + (size_t)(p - lane) * 8);
    }
  };

  stage(0, 0);
  for (int t = 0; t < 64; ++t) {
    __syncthreads();  // stage(t) complete (vmcnt drain); compute(t-1) reads done
    if (t + 1 < 64) stage((t + 1) * 32, (t + 1) & 1);
    const u16* Asb = As[t & 1];
    const u16* Bsb = Bs[t & 1];
    s16x8 a[4];
#pragma unroll
    for (int mt = 0; mt < 4; ++mt) {
      int r = wm * 64 + mt * 16 + ln;
      a[mt] = *(const s16x8*)(Asb + r * 32 + ((quad ^ (r & 3)) * 8));
    }
#pragma unroll
    for (int nt = 0; nt < 4; ++nt) {
      int r = wn * 64 + nt * 16 + ln;
      s16x8 bf = *(const s16x8*)(Bsb + r * 32 + ((quad ^ (r & 3)) * 8));
#pragma unroll
      for (int mt = 0; mt < 4; ++mt) acc[mt][nt] = mfma16(a[mt], bf, acc[mt][nt]);
    }
  }
#pragma unroll
  for (int mt = 0; mt < 4; ++mt)
#pragma unroll
    for (int nt = 0; nt < 4; ++nt) {
      int row0 = m0 + wm * 64 + mt * 16 + quad * 4;
      int col = n0 + wn * 64 + nt * 16 + ln;
      int sel = col >> 8, c = col & 255;
      u16x4 vv;
#pragma unroll
      for (int jj = 0; jj < 4; ++jj) vv[jj] = bf16rne(acc[mt][nt][jj]);
      if (sel == 2) {
        int b = row0 >> 12, s = row0 & 4095;
        *(u16x4*)(Vt + (size_t)b * 1048576 + (size_t)c * 4096 + s) = vv;
      } else {
        u16* dst = (sel == 0) ? Qb : Kb;
#pragma unroll
        for (int jj = 0; jj < 4; ++jj) dst[(size_t)(row0 + jj) * 256 + c] = vv[jj];
      }
    }
}

// ------- fused flash attention: 64 q-rows/block, 8 waves, dbuf staging -------
// R5/R6/R8-proven: ~123 us, MfmaUtil 38, no spills. Unchanged this round.
__global__ __launch_bounds__(512, 2) void attn_kernel(const u16* __restrict__ Qb,
                                                      const u16* __restrict__ Kb,
                                                      const u16* __restrict__ Vt,
                                                      const float* __restrict__ lamp,
                                                      float* __restrict__ out) {
  const int bid = blockIdx.x;
  const int xcd = bid & 7;
  const int b = xcd >> 1;
  const int qt = ((bid >> 3) << 1) + (xcd & 1);  // 0..63, q rows qt*64..+64
  const int tid = threadIdx.x, lane = tid & 63, w = tid >> 6;
  const int l5 = lane & 31, lh = lane >> 5;
  const int m = w & 1, kt = (w >> 1) & 1, qh = w >> 2;

  // dbuf: two 64KB buffers [Ks 32KB | Vs 32KB]; epilogue overlays the lot.
  __shared__ __align__(16) char smem[134144];
  float* buf0 = (float*)smem;            // epilogue: map0 O^T [256][65]
  float* buf1 = (float*)(smem + 66560);  // epilogue: map1 O^T [256][65]
  float* ls = (float*)(smem + 133120);   // l partials [w][32]

  const u16* Kg0 = Kb + ((size_t)b * 4096) * 256;
  const u16* Vg0 = Vt + (size_t)b * 1048576;

  auto stage = [&](int kb, char* base) {
    u16* Ks = (u16*)base;
    u16* Vs = (u16*)(base + 32768);
#pragma unroll
    for (int i = 0; i < 4; ++i) {
      int p = tid + i * 512;
      int row = p >> 5, c = p & 31;
      int cg = (c & 16) | ((c ^ row) & 15);
      gl_lds16(Kg0 + (size_t)(kb + row) * 256 + cg * 8, Ks + (size_t)(p - lane) * 8);
    }
#pragma unroll
    for (int i = 0; i < 4; ++i) {
      int p = tid + i * 512;
      int row = p >> 3, c = p & 7;
      int cg = c ^ (row & 7);
      gl_lds16(Vg0 + (size_t)row * 4096 + kb + cg * 8, Vs + (size_t)(p - lane) * 8);
    }
  };

  // kick off tile 0 staging before anything else
  stage(0, smem);

  // Q^T B-frags: B[k=d][n=q]: lane q = l5 within slice qh, d = s*16 + lh*8 + j
  s16x8 bq[8];
  {
    const u16* qp =
        Qb + ((size_t)(b * 4096 + qt * 64 + qh * 32 + l5)) * 256 + m * 128 + lh * 8;
#pragma unroll
    for (int s = 0; s < 8; ++s) bq[s] = *(const s16x8*)(qp + s * 16);
  }

  f32x16 O[8];
#pragma unroll
  for (int ct = 0; ct < 8; ++ct)
#pragma unroll
    for (int r = 0; r < 16; ++r) O[ct][r] = 0.f;
  float l_run = 0.f;

  for (int t = 0; t < 64; ++t) {
    __syncthreads();  // stage(t) complete (vmcnt drain); compute(t-1) reads done
    if (t + 1 < 64) stage((t + 1) * 64, smem + ((t + 1) & 1) * 65536);

    char* base = smem + (t & 1) * 65536;
    u16* Ks = (u16*)base;
    u16* Vs = (u16*)(base + 32768);

    // S^T[32 keys][32 q] = K . Q^T for (map m, keys kt*32..+32); two chains
    f32x16 Sa, Sb;
#pragma unroll
    for (int r = 0; r < 16; ++r) { Sa[r] = 0.f; Sb[r] = 0.f; }
#pragma unroll
    for (int s = 0; s < 8; s += 2) {
      int row = kt * 32 + l5;
      int c0 = m * 16 + s * 2 + lh;
      int c1 = m * 16 + (s + 1) * 2 + lh;
      s16x8 a0 = *(const s16x8*)(Ks + row * 256 + (((c0 & 16) | ((c0 ^ row) & 15))) * 8);
      s16x8 a1 = *(const s16x8*)(Ks + row * 256 + (((c1 & 16) | ((c1 ^ row) & 15))) * 8);
      Sa = mfma32(a0, bq[s], Sa);
      Sb = mfma32(a1, bq[s + 1], Sb);
    }

    // pre-read all V frags into regs (PV becomes pure-reg; hides LDS latency)
    s16x8 vfr0[8], vfr1[8];
#pragma unroll
    for (int ct = 0; ct < 8; ++ct) {
      int row = ct * 32 + l5;
      int c0v = (kt * 32) / 8 + lh;
      int c1v = (kt * 32 + 16) / 8 + lh;
      vfr0[ct] = *(const s16x8*)(Vs + row * 64 + ((c0v ^ (row & 7)) * 8));
      vfr1[ct] = *(const s16x8*)(Vs + row * 64 + ((c1v ^ (row & 7)) * 8));
    }

    // p = exp2(s) via raw v_exp_f32; accumulate l; pack to dwords (bf16rne)
    uint32_t P[8];
#pragma unroll
    for (int d = 0; d < 8; ++d) {
      float p0 = __builtin_amdgcn_exp2f(Sa[2 * d] + Sb[2 * d]);
      float p1 = __builtin_amdgcn_exp2f(Sa[2 * d + 1] + Sb[2 * d + 1]);
      l_run += p0 + p1;
      P[d] = (uint32_t)bf16rne(p0) | ((uint32_t)bf16rne(p1) << 16);
    }

    // PV: O^T[256 vcol][32 q] += V^T . P^T ; half-exchange via permlane32_swap:
    // swap(P[4k],P[4k+2]) -> (fd0,fd2), swap(P[4k+1],P[4k+3]) -> (fd1,fd3)
#pragma unroll
    for (int ks = 0; ks < 2; ++ks) {
      u32x2 s02 = __builtin_amdgcn_permlane32_swap(P[ks * 4 + 0], P[ks * 4 + 2], false, false);
      u32x2 s13 = __builtin_amdgcn_permlane32_swap(P[ks * 4 + 1], P[ks * 4 + 3], false, false);
      u32x4 fd;
      fd[0] = s02[0]; fd[1] = s13[0]; fd[2] = s02[1]; fd[3] = s13[1];
      s16x8 pf = __builtin_bit_cast(s16x8, fd);
      if (ks == 0) {
#pragma unroll
        for (int ct = 0; ct < 8; ++ct) O[ct] = mfma32(vfr0[ct], pf, O[ct]);
      } else {
#pragma unroll
        for (int ct = 0; ct < 8; ++ct) O[ct] = mfma32(vfr1[ct], pf, O[ct]);
      }
    }
  }

  // ---------------- epilogue ----------------
  float lam = *lamp;
  l_run += __shfl_xor(l_run, 32);  // fold lh (partner holds other 16 keys)
  __syncthreads();                 // B1: loop reads done; smem becomes buf0/buf1/ls
  if (lane < 32) ls[w * 32 + l5] = l_run;
  float* bufm = m ? buf1 : buf0;
  const int qb0 = qh * 32;
  if (kt == 1) {
#pragma unroll
    for (int ct = 0; ct < 8; ++ct)
#pragma unroll
      for (int r = 0; r < 16; ++r) {
        int vcol = ct * 32 + (r & 3) + 8 * (r >> 2) + 4 * lh;
        bufm[vcol * 65 + qb0 + l5] = O[ct][r];
      }
  }
  __syncthreads();  // B2
  if (kt == 0) {
    float linv = 1.f / (ls[w * 32 + l5] + ls[(w | 2) * 32 + l5]);
#pragma unroll
    for (int ct = 0; ct < 8; ++ct)
#pragma unroll
      for (int r = 0; r < 16; ++r) {
        int vcol = ct * 32 + (r & 3) + 8 * (r >> 2) + 4 * lh;
        bufm[vcol * 65 + qb0 + l5] = (O[ct][r] + bufm[vcol * 65 + qb0 + l5]) * linv;
      }
  }
  __syncthreads();  // B3
  // cooperative write: out[q][col], coalesced; 512 threads = 2 q-halves x 256 cols
  float* og = out + ((size_t)(b * 4096 + qt * 64)) * 256;
  const int col = tid & 255, half = tid >> 8;
#pragma unroll
  for (int j2 = 0; j2 < 32; ++j2) {
    int q = half * 32 + j2;
    float v = buf0[col * 65 + q] - lam * buf1[col * 65 + q];
    og[(size_t)q * 256 + col] = v;
  }
}

extern "C" void kernel_launch(void* const* d_in, const int* in_sizes, int n_in,
                              void* d_out, int out_size, void* d_ws, size_t ws_size,
                              hipStream_t stream) {
  (void)in_sizes; (void)n_in; (void)out_size; (void)ws_size;
  const float* x   = (const float*)d_in[0];
  const float* WQ  = (const float*)d_in[1];
  const float* WK  = (const float*)d_in[2];
  const float* WV  = (const float*)d_in[3];
  const float* lq1 = (const float*)d_in[4];
  const float* lq2 = (const float*)d_in[5];
  const float* lk1 = (const float*)d_in[6];
  const float* lk2 = (const float*)d_in[7];
  float* out = (float*)d_out;

  char* ws = (char*)d_ws;
  u16* xb = (u16*)ws;   ws += (size_t)16384 * 2048 * 2;
  u16* Wt = (u16*)ws;   ws += (size_t)768 * 2048 * 2;
  u16* Qb = (u16*)ws;   ws += (size_t)16384 * 256 * 2;
  u16* Kb = (u16*)ws;   ws += (size_t)16384 * 256 * 2;
  u16* Vt = (u16*)ws;   ws += (size_t)16384 * 256 * 2;  // [b][col 256][s 4096]
  float* lamp = (float*)ws;

  const float qscale = 0.0883883476f * 1.44269504f;  // HEAD_DIM^-0.5 * log2(e)

  hipLaunchKernelGGL(pre_kernel, dim3(22529), dim3(256), 0, stream,
                     x, WQ, WK, WV, lq1, lq2, lk1, lk2, xb, Wt, lamp, qscale);
  hipLaunchKernelGGL(proj_gemm, dim3(768), dim3(256), 0, stream, xb, Wt, Qb, Kb, Vt);
  hipLaunchKernelGGL(attn_kernel, dim3(256), dim3(512), 0, stream, Qb, Kb, Vt, lamp, out);
}